// Round 5
// baseline (228.204 us; speedup 1.0000x reference)
//
#include <hip/hip_runtime.h>
#include <hip/hip_cooperative_groups.h>

namespace cg = cooperative_groups;

#define SLOPE 0.1f
#define EPS 1e-5f

typedef __bf16 bf16x8 __attribute__((ext_vector_type(8)));
typedef unsigned short u16x8 __attribute__((ext_vector_type(8)));
typedef float f32x4 __attribute__((ext_vector_type(4)));
typedef unsigned u32x4 __attribute__((ext_vector_type(4)));

// ---- workspace layout ----
// float offsets on (float*)ws:
#define WS_ESC 0        // 32 : (unused; kept for layout stability)
#define WS_ESH 32       // 32
#define WS_A 64         // 512 : dot(xn_i, ev[0:64])
#define WS_B 576        // 512 : dot(xn_j, ev[96:160])
#define WS_XN 1088      // 512*64 post-lrelu node feats
#define WS_NEWX 33856   // 512*64 pre-BN new_x
#define WS_P1B 66624    // 512*80 : b_h2[k] + x_i . W_h2[k][0:64]
#define WS_SC 107584    // (dead)
#define WS_PART 369728  // 64 floats: [0:32]=col sums, [32:64]=col sumsq (atomic)
// u16 offsets on (unsigned short*)ws (float end 402496 -> u16 804992).
// Weight tables FRAG-MAJOR: element (t, lane l, jj) at [t*512 + l*8 + jj],
// i.e. MFMA B-frag value: n = t*16 + (l&15), k = (l>>4)*8 + jj.
#define WSH_WB 804992   // 2*2560 : GEMM1 B chunks 0,1 (W_h2 cols 64:96, 96:128)
#define WSH_WB2 810112  // 2560   : GEMM1 B chunk 2    (W_h2 cols 128:160)
#define WSH_WO 812672   // 3072   : GEMM2 B (W_eo, k padded to 96)
#define WSH_XB 815744   // 512*64 bf16 copy of x (row-major)
#define WSH_NE 848512   // 262144 edges * 16 u32 (col c | col c+16), bf16 packed

__device__ __forceinline__ float lrelu(float v) { return v > 0.f ? v : SLOPE * v; }
__device__ __forceinline__ unsigned short f2bf(float f) {
  unsigned x = __float_as_uint(f);
  return (unsigned short)((x + 0x7fffu + ((x >> 16) & 1u)) >> 16);
}
__device__ __forceinline__ float bf2f(unsigned short u) {
  return __uint_as_float(((unsigned)u) << 16);
}

// ================= MERGED cooperative kernel =================
// Phase 1 = old k1 (copies, weight repack, xn GEMM, P1B MFMA)
// grid.sync()
// Phase 2 = old k2 (one row per block iteration: edge MLP + softmax + att@xn)
// grid.sync()
// Phase 3 = old k5 (node BN + edge BN apply)
// All phase loops are grid-stride: correct for any grid size G.
__global__ void __launch_bounds__(512) kall(
    const float* __restrict__ x, const float* __restrict__ ea,
    const int* __restrict__ mask, const float* __restrict__ W_nu,
    const float* __restrict__ b_nu, const float* __restrict__ W_h2,
    const float* __restrict__ b_h2, const float* __restrict__ W_eo,
    const float* __restrict__ b_eo, const float* __restrict__ ev,
    const float* __restrict__ bn_n_w, const float* __restrict__ bn_n_b,
    const float* __restrict__ bn_e_w, const float* __restrict__ bn_e_b,
    float* ws, float* __restrict__ out) {
  cg::grid_group gg = cg::this_grid();
  __shared__ union __attribute__((aligned(16))) {
    float wnu[64 * 65];  // phase 1
    struct {             // phase 2
      unsigned short wlds[10752];
      unsigned short ht[128 * 104];
      float p1s[80];
      float s_row[512];
      float red[8];
      float nx[8][64];
      float wred[2][8][32];
    } p2;
    struct {  // phase 3
      float s1[8][64];
      float s2[8][64];
      float scl[64];
      float shf[64];
      float escsh[64];
    } p3;
  } sh;

  int tid = threadIdx.x, blk = blockIdx.x;
  int G = gridDim.x;
  int gtid = blk * 512 + tid, gstride = G * 512;
  unsigned short* wsh = (unsigned short*)ws;

  // ---------- Phase 1a: copies + weight repack + zero stats ----------
  for (int idx = gtid; idx < 32768; idx += gstride) wsh[WSH_XB + idx] = f2bf(x[idx]);
  for (int idx = gtid; idx < 10752; idx += gstride) {
    if (idx < 5120) {
      int c = idx / 2560, r = idx - c * 2560;
      int t = r >> 9, l = (r >> 3) & 63, jj = r & 7;
      int n = t * 16 + (l & 15);
      int k = (l >> 4) * 8 + jj + c * 32;
      wsh[WSH_WB + idx] = f2bf(W_h2[n * 160 + 64 + k]);
    } else if (idx < 7680) {
      int i2 = idx - 5120;
      int t = i2 >> 9, l = (i2 >> 3) & 63, jj = i2 & 7;
      int n = t * 16 + (l & 15);
      int k = (l >> 4) * 8 + jj;
      wsh[WSH_WB2 + i2] = f2bf(W_h2[n * 160 + 128 + k]);
    } else {
      int i3 = idx - 7680;
      int t2 = i3 / 1536, r2 = i3 - t2 * 1536;
      int s = r2 >> 9, l = (r2 >> 3) & 63, jj = r2 & 7;
      int n = t2 * 16 + (l & 15);
      int k = s * 32 + (l >> 4) * 8 + jj;
      wsh[WSH_WO + i3] = (k < 80) ? f2bf(W_eo[n * 80 + k]) : (unsigned short)0;
    }
  }
  if (gtid < 64) ws[WS_PART + gtid] = 0.f;

  // ---------- Phase 1b: xn = lrelu(x @ W_nu^T + b) + a/b scalars ----------
  {
#pragma unroll
    for (int it = 0; it < 8; it++) {
      int idx = it * 512 + tid;
      sh.wnu[(idx >> 6) * 65 + (idx & 63)] = W_nu[idx];
    }
    __syncthreads();
    int c = tid & 63;
    for (int r0 = blk * 8; r0 < 512; r0 += G * 8) {
      int i = r0 + (tid >> 6);
      float acc = b_nu[c];
      const float* xr = x + i * 64;
#pragma unroll 8
      for (int k = 0; k < 64; k++) acc += xr[k] * sh.wnu[c * 65 + k];
      float xnv = lrelu(acc);
      ws[WS_XN + i * 64 + c] = xnv;
      float va = xnv * ev[c];
      float vb = xnv * ev[96 + c];
#pragma unroll
      for (int off = 32; off >= 1; off >>= 1) {
        va += __shfl_xor(va, off, 64);
        vb += __shfl_xor(vb, off, 64);
      }
      if (c == 0) { ws[WS_A + i] = va; ws[WS_B + i] = vb; }
    }
  }

  // ---------- Phase 1c: P1B via MFMA (M=512 x N=80, K=64) ----------
  {
    int stid = tid & 255;
    int wave = stid >> 6, lane = stid & 63;
    int c16 = lane & 15, q = lane >> 4;
    for (int u = blk * 2 + (tid >> 8); u < 40; u += G * 2) {
      int bm = u & 7, bn = u >> 3;
      int n = bn * 16 + c16;  // 0..79
      const float* wrow = W_h2 + n * 160;
      int mrow = bm * 64 + wave * 16 + c16;
      bf16x8 bfr[2], afr[2];
#pragma unroll
      for (int ks = 0; ks < 2; ks++) {
        const float* bs = wrow + ks * 32 + q * 8;
        const float* as = x + mrow * 64 + ks * 32 + q * 8;
        u16x8 ub, ua;
#pragma unroll
        for (int jj = 0; jj < 8; jj++) { ub[jj] = f2bf(bs[jj]); ua[jj] = f2bf(as[jj]); }
        bfr[ks] = __builtin_bit_cast(bf16x8, ub);
        afr[ks] = __builtin_bit_cast(bf16x8, ua);
      }
      float bias = b_h2[n];
      f32x4 acc = {bias, bias, bias, bias};
      acc = __builtin_amdgcn_mfma_f32_16x16x32_bf16(afr[0], bfr[0], acc, 0, 0, 0);
      acc = __builtin_amdgcn_mfma_f32_16x16x32_bf16(afr[1], bfr[1], acc, 0, 0, 0);
#pragma unroll
      for (int r = 0; r < 4; r++) {
        int mm = bm * 64 + wave * 16 + q * 4 + r;
        ws[WS_P1B + mm * 80 + n] = acc[r];
      }
    }
  }

  gg.sync();

  // ---------- Phase 2: per row i — edge MLP + softmax + att@xn ----------
  {
    int w = tid >> 6, lane = tid & 63;
    int c16 = lane & 15, q = lane >> 4;
    unsigned* ne32 = (unsigned*)(wsh + WSH_NE);
    // stage weights once (same for all rows)
#pragma unroll
    for (int it = 0; it < 3; it++) {
      int idx = it * 512 + tid;
      if (idx < 1344)
        *(u16x8*)&sh.p2.wlds[idx * 8] = *(const u16x8*)(wsh + WSH_WB + idx * 8);
    }
    float beo0 = b_eo[c16], beo1 = b_eo[16 + c16];
    float eve0 = ev[64 + c16], eve1 = ev[80 + c16];

    for (int i = blk; i < 512; i += G) {
      if (tid < 80) sh.p2.p1s[tid] = ws[WS_P1B + i * 80 + tid];
      float a_i = ws[WS_A + i];
      __syncthreads();  // p1s + wlds ready; also orders vs prev iteration

      float scs0 = 0.f, scss0 = 0.f, scs1 = 0.f, scss1 = 0.f;
#pragma unroll
      for (int h = 0; h < 4; h++) {
        int jb = w * 64 + h * 16;
        bf16x8 af0;
        {
          const float* src = ea + (i * 512 + jb + c16) * 32 + q * 8;
          f32x4 e0 = *(const f32x4*)src;
          f32x4 e1 = *(const f32x4*)(src + 4);
          u16x8 u;
#pragma unroll
          for (int jj = 0; jj < 4; jj++) { u[jj] = f2bf(e0[jj]); u[4 + jj] = f2bf(e1[jj]); }
          af0 = __builtin_bit_cast(bf16x8, u);
        }
        bf16x8 af1 = __builtin_bit_cast(
            bf16x8, *(const u16x8*)(wsh + WSH_XB + (jb + c16) * 64 + q * 8));
        bf16x8 af2 = __builtin_bit_cast(
            bf16x8, *(const u16x8*)(wsh + WSH_XB + (jb + c16) * 64 + 32 + q * 8));
        int4 mk = *(const int4*)(mask + i * 512 + jb + q * 4);
        int mkv[4];
        mkv[0] = mk.x; mkv[1] = mk.y; mkv[2] = mk.z; mkv[3] = mk.w;

        f32x4 acc[5];
#pragma unroll
        for (int t = 0; t < 5; t++) {
          float p1v = sh.p2.p1s[t * 16 + c16];
          acc[t] = {p1v, p1v, p1v, p1v};
        }
#pragma unroll
        for (int t = 0; t < 5; t++) {
          bf16x8 wb =
              __builtin_bit_cast(bf16x8, *(const u16x8*)&sh.p2.wlds[t * 512 + lane * 8]);
          acc[t] = __builtin_amdgcn_mfma_f32_16x16x32_bf16(af0, wb, acc[t], 0, 0, 0);
        }
#pragma unroll
        for (int t = 0; t < 5; t++) {
          bf16x8 wb = __builtin_bit_cast(
              bf16x8, *(const u16x8*)&sh.p2.wlds[2560 + t * 512 + lane * 8]);
          acc[t] = __builtin_amdgcn_mfma_f32_16x16x32_bf16(af1, wb, acc[t], 0, 0, 0);
        }
#pragma unroll
        for (int t = 0; t < 5; t++) {
          bf16x8 wb = __builtin_bit_cast(
              bf16x8, *(const u16x8*)&sh.p2.wlds[5120 + t * 512 + lane * 8]);
          acc[t] = __builtin_amdgcn_mfma_f32_16x16x32_bf16(af2, wb, acc[t], 0, 0, 0);
        }
#pragma unroll
        for (int t = 0; t < 5; t++)
#pragma unroll
          for (int r = 0; r < 4; r++)
            sh.p2.ht[(w * 16 + q * 4 + r) * 104 + t * 16 + c16] = f2bf(lrelu(acc[t][r]));

        f32x4 acc2[2] = {{0.f, 0.f, 0.f, 0.f}, {0.f, 0.f, 0.f, 0.f}};
        int hrow = w * 16 + c16;
#pragma unroll
        for (int s = 0; s < 3; s++) {
          int kk = s * 32 + q * 8;
          u16x8 hb = {0, 0, 0, 0, 0, 0, 0, 0};
          if (kk < 80) hb = *(const u16x8*)&sh.p2.ht[hrow * 104 + kk];
          bf16x8 ha = __builtin_bit_cast(bf16x8, hb);
          bf16x8 wo0 = __builtin_bit_cast(
              bf16x8, *(const u16x8*)&sh.p2.wlds[7680 + s * 512 + lane * 8]);
          bf16x8 wo1 = __builtin_bit_cast(
              bf16x8, *(const u16x8*)&sh.p2.wlds[7680 + 1536 + s * 512 + lane * 8]);
          acc2[0] = __builtin_amdgcn_mfma_f32_16x16x32_bf16(ha, wo0, acc2[0], 0, 0, 0);
          acc2[1] = __builtin_amdgcn_mfma_f32_16x16x32_bf16(ha, wo1, acc2[1], 0, 0, 0);
        }

        float se[4];
#pragma unroll
        for (int r = 0; r < 4; r++) {
          int m = i * 512 + jb + q * 4 + r;
          float mf = mkv[r] ? 1.f : 0.f;
          float v0 = lrelu(acc2[0][r] + beo0) * mf;
          float v1 = lrelu(acc2[1][r] + beo1) * mf;
          scs0 += v0; scss0 += v0 * v0;
          scs1 += v1; scss1 += v1 * v1;
          ne32[m * 16 + c16] = (unsigned)f2bf(v0) | ((unsigned)f2bf(v1) << 16);
          float s = v0 * eve0 + v1 * eve1;
#pragma unroll
          for (int off = 8; off >= 1; off >>= 1) s += __shfl_xor(s, off, 64);
          se[r] = s;
        }
        if (c16 < 4) {
          int j = jb + q * 4 + c16;
          float s = (c16 == 0) ? se[0] : (c16 == 1) ? se[1] : (c16 == 2) ? se[2] : se[3];
          sh.p2.s_row[j] = lrelu(a_i + ws[WS_B + j] + s);
        }
      }

      // wave stats -> wred
      scs0 += __shfl_xor(scs0, 16, 64); scs0 += __shfl_xor(scs0, 32, 64);
      scss0 += __shfl_xor(scss0, 16, 64); scss0 += __shfl_xor(scss0, 32, 64);
      scs1 += __shfl_xor(scs1, 16, 64); scs1 += __shfl_xor(scs1, 32, 64);
      scss1 += __shfl_xor(scss1, 16, 64); scss1 += __shfl_xor(scss1, 32, 64);
      if (q == 0) {
        sh.p2.wred[0][w][c16] = scs0; sh.p2.wred[0][w][16 + c16] = scs1;
        sh.p2.wred[1][w][c16] = scss0; sh.p2.wred[1][w][16 + c16] = scss1;
      }
      __syncthreads();  // s_row + wred complete

      // softmax (no max-subtraction: scores bounded; shift-invariant)
      float p = __expf(sh.p2.s_row[tid]);
      float sm = p;
#pragma unroll
      for (int off = 32; off >= 1; off >>= 1) sm += __shfl_xor(sm, off, 64);
      if (lane == 0) sh.p2.red[w] = sm;
      __syncthreads();
      float tot = sh.p2.red[0] + sh.p2.red[1] + sh.p2.red[2] + sh.p2.red[3] +
                  sh.p2.red[4] + sh.p2.red[5] + sh.p2.red[6] + sh.p2.red[7];
      float attv = p * (1.f / tot) * (mask[i * 512 + tid] ? 1.f : 0.f);
      __syncthreads();  // all reads of s_row (scores) done
      sh.p2.s_row[tid] = attv;
      __syncthreads();

      // att @ xn : wave w covers j in [w*64, (w+1)*64)
      const float* xn = ws + WS_XN;
      float accv = 0.f;
#pragma unroll 4
      for (int u = 0; u < 64; u++) {
        int j = w * 64 + u;
        accv += sh.p2.s_row[j] * xn[j * 64 + lane];
      }
      sh.p2.nx[w][lane] = accv;
      __syncthreads();
      if (tid < 64) {
        float s = 0.f;
#pragma unroll
        for (int w2 = 0; w2 < 8; w2++) s += sh.p2.nx[w2][tid];
        ws[WS_NEWX + i * 64 + tid] = s;
        int half = tid >> 5, col = tid & 31;
        float v = 0.f;
#pragma unroll
        for (int w2 = 0; w2 < 8; w2++) v += sh.p2.wred[half][w2][col];
        atomicAdd(&ws[WS_PART + tid], v);
      }
    }
  }

  gg.sync();

  // ---------- Phase 3: node BN (blocks 0..7) + edge BN apply (all blocks) ----------
  {
    if (tid < 32) {
      float sum = ws[WS_PART + tid];
      float ssq = ws[WS_PART + 32 + tid];
      float mean = sum * (1.f / 262144.f);
      float var = ssq * (1.f / 262144.f) - mean * mean;
      float s = bn_e_w[tid] * rsqrtf(fmaxf(var, 0.f) + EPS);
      sh.p3.escsh[tid] = s;
      sh.p3.escsh[32 + tid] = bn_e_b[tid] - mean * s;
    }
    if (blk < 8) {
      int c = tid & 63, g = tid >> 6;
      float a = 0.f, b = 0.f;
#pragma unroll 4
      for (int u = 0; u < 64; u++) {
        float v = ws[WS_NEWX + (g * 64 + u) * 64 + c];
        a += v;
        b += v * v;
      }
      sh.p3.s1[g][c] = a;
      sh.p3.s2[g][c] = b;
      __syncthreads();
      if (tid < 64) {
        float sum = 0.f, ssq = 0.f;
#pragma unroll
        for (int g2 = 0; g2 < 8; g2++) { sum += sh.p3.s1[g2][tid]; ssq += sh.p3.s2[g2][tid]; }
        float mean = sum * (1.f / 512.f);
        float var = ssq * (1.f / 512.f) - mean * mean;
        float s = bn_n_w[tid] * rsqrtf(fmaxf(var, 0.f) + EPS);
        sh.p3.scl[tid] = s;
        sh.p3.shf[tid] = bn_n_b[tid] - mean * s;
      }
      __syncthreads();
#pragma unroll
      for (int u = 0; u < 8; u++) {
        int idx = blk * 4096 + u * 512 + tid;
        int c2 = idx & 63;
        out[idx] = ws[WS_NEWX + idx] * sh.p3.scl[c2] + sh.p3.shf[c2];
      }
    }
    __syncthreads();  // escsh visible to whole block
    const unsigned* ne32c = (const unsigned*)(wsh + WSH_NE);
    int cb = (tid & 3) << 2;  // constant per thread (stride multiple of 4)
    f32x4 esc0 = *(const f32x4*)&sh.p3.escsh[cb];
    f32x4 esc1 = *(const f32x4*)&sh.p3.escsh[16 + cb];
    f32x4 esh0 = *(const f32x4*)&sh.p3.escsh[32 + cb];
    f32x4 esh1 = *(const f32x4*)&sh.p3.escsh[48 + cb];
    float* oe = out + 32768;
    for (int it2 = gtid; it2 < 1048576; it2 += gstride) {
      int b4 = it2 * 4;
      u32x4 raw = *(const u32x4*)(ne32c + b4);
      int e32 = (b4 >> 4) * 32;
      f32x4 lo, hi;
#pragma unroll
      for (int u = 0; u < 4; u++) {
        lo[u] = bf2f((unsigned short)(raw[u] & 0xffffu)) * esc0[u] + esh0[u];
        hi[u] = bf2f((unsigned short)(raw[u] >> 16)) * esc1[u] + esh1[u];
      }
      *(f32x4*)(oe + e32 + cb) = lo;
      *(f32x4*)(oe + e32 + 16 + cb) = hi;
    }
  }
}

// ================= Fallback path (r4 kernels, unchanged) =================
__global__ void __launch_bounds__(256) k1(const float* __restrict__ x,
                                          const float* __restrict__ W_nu,
                                          const float* __restrict__ b_nu,
                                          const float* __restrict__ W_h2,
                                          const float* __restrict__ b_h2,
                                          const float* __restrict__ W_eo,
                                          const float* __restrict__ ev,
                                          float* ws) {
  int blk = blockIdx.x;
  int tid = threadIdx.x;
  unsigned short* wsh = (unsigned short*)ws;
  if (blk < 128) {
    __shared__ float wlds[64 * 65];
#pragma unroll
    for (int it = 0; it < 16; it++) {
      int idx = it * 256 + tid;
      wlds[(idx >> 6) * 65 + (idx & 63)] = W_nu[idx];
    }
    int gid = blk * 256 + tid;
    wsh[WSH_XB + gid] = f2bf(x[gid]);
    if (gid < 64) ws[WS_PART + gid] = 0.f;
    if (gid < 5120) {
      int c = gid / 2560, r = gid - c * 2560;
      int t = r >> 9, l = (r >> 3) & 63, jj = r & 7;
      int n = t * 16 + (l & 15);
      int k = (l >> 4) * 8 + jj + c * 32;
      wsh[WSH_WB + gid] = f2bf(W_h2[n * 160 + 64 + k]);
    } else if (gid < 7680) {
      int idx = gid - 5120;
      int t = idx >> 9, l = (idx >> 3) & 63, jj = idx & 7;
      int n = t * 16 + (l & 15);
      int k = (l >> 4) * 8 + jj;
      wsh[WSH_WB2 + idx] = f2bf(W_h2[n * 160 + 128 + k]);
    } else if (gid < 10752) {
      int idx = gid - 7680;
      int t2 = idx / 1536, r2 = idx - t2 * 1536;
      int s = r2 >> 9, l = (r2 >> 3) & 63, jj = r2 & 7;
      int n = t2 * 16 + (l & 15);
      int k = s * 32 + (l >> 4) * 8 + jj;
      wsh[WSH_WO + idx] = (k < 80) ? f2bf(W_eo[n * 80 + k]) : (unsigned short)0;
    }
    __syncthreads();
    int i = blk * 4 + (tid >> 6);
    int c = tid & 63;
    float acc = b_nu[c];
    const float* xr = x + i * 64;
#pragma unroll 8
    for (int k = 0; k < 64; k++) acc += xr[k] * wlds[c * 65 + k];
    float xnv = lrelu(acc);
    ws[WS_XN + i * 64 + c] = xnv;
    float va = xnv * ev[c];
    float vb = xnv * ev[96 + c];
#pragma unroll
    for (int off = 32; off >= 1; off >>= 1) {
      va += __shfl_xor(va, off, 64);
      vb += __shfl_xor(vb, off, 64);
    }
    if (c == 0) { ws[WS_A + i] = va; ws[WS_B + i] = vb; }
  } else {
    int b2 = blk - 128;
    int bm = b2 & 7, bn = b2 >> 3;
    int wave = tid >> 6, lane = tid & 63;
    int c16 = lane & 15, q = lane >> 4;
    int n = bn * 16 + c16;
    const float* wrow = W_h2 + n * 160;
    int mrow = bm * 64 + wave * 16 + c16;
    bf16x8 bfr[2], afr[2];
#pragma unroll
    for (int ks = 0; ks < 2; ks++) {
      const float* bs = wrow + ks * 32 + q * 8;
      const float* as = x + mrow * 64 + ks * 32 + q * 8;
      u16x8 ub, ua;
#pragma unroll
      for (int jj = 0; jj < 8; jj++) { ub[jj] = f2bf(bs[jj]); ua[jj] = f2bf(as[jj]); }
      bfr[ks] = __builtin_bit_cast(bf16x8, ub);
      afr[ks] = __builtin_bit_cast(bf16x8, ua);
    }
    float bias = b_h2[n];
    f32x4 acc = {bias, bias, bias, bias};
    acc = __builtin_amdgcn_mfma_f32_16x16x32_bf16(afr[0], bfr[0], acc, 0, 0, 0);
    acc = __builtin_amdgcn_mfma_f32_16x16x32_bf16(afr[1], bfr[1], acc, 0, 0, 0);
#pragma unroll
    for (int r = 0; r < 4; r++) {
      int mm = bm * 64 + wave * 16 + q * 4 + r;
      ws[WS_P1B + mm * 80 + n] = acc[r];
    }
  }
}

__global__ void __launch_bounds__(512) k2(const float* __restrict__ ea,
                                          const int* __restrict__ mask,
                                          const float* __restrict__ b_eo,
                                          const float* __restrict__ ev,
                                          float* ws) {
  __shared__ unsigned short wlds[10752];
  __shared__ unsigned short ht[128 * 104];
  __shared__ float p1s[80];
  __shared__ float s_row[512];
  __shared__ float red[8];
  __shared__ float nx[8][64];
  __shared__ float wred[2][8][32];
  int tid = threadIdx.x;
  int w = tid >> 6, lane = tid & 63;
  int c16 = lane & 15, q = lane >> 4;
  int i = blockIdx.x;
  const unsigned short* wsh = (const unsigned short*)ws;
  unsigned* ne32 = (unsigned*)((unsigned short*)ws + WSH_NE);
#pragma unroll
  for (int it = 0; it < 3; it++) {
    int idx = it * 512 + tid;
    if (idx < 1344) *(u16x8*)&wlds[idx * 8] = *(const u16x8*)(wsh + WSH_WB + idx * 8);
  }
  if (tid < 80) p1s[tid] = ws[WS_P1B + i * 80 + tid];
  float beo0 = b_eo[c16], beo1 = b_eo[16 + c16];
  float eve0 = ev[64 + c16], eve1 = ev[80 + c16];
  float a_i = ws[WS_A + i];
  __syncthreads();
  float scs0 = 0.f, scss0 = 0.f, scs1 = 0.f, scss1 = 0.f;
#pragma unroll
  for (int h = 0; h < 4; h++) {
    int jb = w * 64 + h * 16;
    bf16x8 af0;
    {
      const float* src = ea + (i * 512 + jb + c16) * 32 + q * 8;
      f32x4 e0 = *(const f32x4*)src;
      f32x4 e1 = *(const f32x4*)(src + 4);
      u16x8 u;
#pragma unroll
      for (int jj = 0; jj < 4; jj++) { u[jj] = f2bf(e0[jj]); u[4 + jj] = f2bf(e1[jj]); }
      af0 = __builtin_bit_cast(bf16x8, u);
    }
    bf16x8 af1 = __builtin_bit_cast(
        bf16x8, *(const u16x8*)(wsh + WSH_XB + (jb + c16) * 64 + q * 8));
    bf16x8 af2 = __builtin_bit_cast(
        bf16x8, *(const u16x8*)(wsh + WSH_XB + (jb + c16) * 64 + 32 + q * 8));
    int4 mk = *(const int4*)(mask + i * 512 + jb + q * 4);
    int mkv[4];
    mkv[0] = mk.x; mkv[1] = mk.y; mkv[2] = mk.z; mkv[3] = mk.w;
    f32x4 acc[5];
#pragma unroll
    for (int t = 0; t < 5; t++) {
      float p1v = p1s[t * 16 + c16];
      acc[t] = {p1v, p1v, p1v, p1v};
    }
#pragma unroll
    for (int t = 0; t < 5; t++) {
      bf16x8 wb = __builtin_bit_cast(bf16x8, *(const u16x8*)&wlds[t * 512 + lane * 8]);
      acc[t] = __builtin_amdgcn_mfma_f32_16x16x32_bf16(af0, wb, acc[t], 0, 0, 0);
    }
#pragma unroll
    for (int t = 0; t < 5; t++) {
      bf16x8 wb =
          __builtin_bit_cast(bf16x8, *(const u16x8*)&wlds[2560 + t * 512 + lane * 8]);
      acc[t] = __builtin_amdgcn_mfma_f32_16x16x32_bf16(af1, wb, acc[t], 0, 0, 0);
    }
#pragma unroll
    for (int t = 0; t < 5; t++) {
      bf16x8 wb =
          __builtin_bit_cast(bf16x8, *(const u16x8*)&wlds[5120 + t * 512 + lane * 8]);
      acc[t] = __builtin_amdgcn_mfma_f32_16x16x32_bf16(af2, wb, acc[t], 0, 0, 0);
    }
#pragma unroll
    for (int t = 0; t < 5; t++)
#pragma unroll
      for (int r = 0; r < 4; r++)
        ht[(w * 16 + q * 4 + r) * 104 + t * 16 + c16] = f2bf(lrelu(acc[t][r]));
    f32x4 acc2[2] = {{0.f, 0.f, 0.f, 0.f}, {0.f, 0.f, 0.f, 0.f}};
    int hrow = w * 16 + c16;
#pragma unroll
    for (int s = 0; s < 3; s++) {
      int kk = s * 32 + q * 8;
      u16x8 hb = {0, 0, 0, 0, 0, 0, 0, 0};
      if (kk < 80) hb = *(const u16x8*)&ht[hrow * 104 + kk];
      bf16x8 ha = __builtin_bit_cast(bf16x8, hb);
      bf16x8 wo0 =
          __builtin_bit_cast(bf16x8, *(const u16x8*)&wlds[7680 + s * 512 + lane * 8]);
      bf16x8 wo1 = __builtin_bit_cast(
          bf16x8, *(const u16x8*)&wlds[7680 + 1536 + s * 512 + lane * 8]);
      acc2[0] = __builtin_amdgcn_mfma_f32_16x16x32_bf16(ha, wo0, acc2[0], 0, 0, 0);
      acc2[1] = __builtin_amdgcn_mfma_f32_16x16x32_bf16(ha, wo1, acc2[1], 0, 0, 0);
    }
    float se[4];
#pragma unroll
    for (int r = 0; r < 4; r++) {
      int m = i * 512 + jb + q * 4 + r;
      float mf = mkv[r] ? 1.f : 0.f;
      float v0 = lrelu(acc2[0][r] + beo0) * mf;
      float v1 = lrelu(acc2[1][r] + beo1) * mf;
      scs0 += v0; scss0 += v0 * v0;
      scs1 += v1; scss1 += v1 * v1;
      ne32[m * 16 + c16] = (unsigned)f2bf(v0) | ((unsigned)f2bf(v1) << 16);
      float s = v0 * eve0 + v1 * eve1;
#pragma unroll
      for (int off = 8; off >= 1; off >>= 1) s += __shfl_xor(s, off, 64);
      se[r] = s;
    }
    if (c16 < 4) {
      int j = jb + q * 4 + c16;
      float s = (c16 == 0) ? se[0] : (c16 == 1) ? se[1] : (c16 == 2) ? se[2] : se[3];
      s_row[j] = lrelu(a_i + ws[WS_B + j] + s);
    }
  }
  scs0 += __shfl_xor(scs0, 16, 64); scs0 += __shfl_xor(scs0, 32, 64);
  scss0 += __shfl_xor(scss0, 16, 64); scss0 += __shfl_xor(scss0, 32, 64);
  scs1 += __shfl_xor(scs1, 16, 64); scs1 += __shfl_xor(scs1, 32, 64);
  scss1 += __shfl_xor(scss1, 16, 64); scss1 += __shfl_xor(scss1, 32, 64);
  if (q == 0) {
    wred[0][w][c16] = scs0; wred[0][w][16 + c16] = scs1;
    wred[1][w][c16] = scss0; wred[1][w][16 + c16] = scss1;
  }
  __syncthreads();
  float p = __expf(s_row[tid]);
  float sm = p;
#pragma unroll
  for (int off = 32; off >= 1; off >>= 1) sm += __shfl_xor(sm, off, 64);
  if (lane == 0) red[w] = sm;
  __syncthreads();
  float tot = red[0] + red[1] + red[2] + red[3] + red[4] + red[5] + red[6] + red[7];
  float attv = p * (1.f / tot) * (mask[i * 512 + tid] ? 1.f : 0.f);
  s_row[tid] = attv;
  __syncthreads();
  const float* xn = ws + WS_XN;
  float accv = 0.f;
#pragma unroll 4
  for (int u = 0; u < 64; u++) {
    int j = w * 64 + u;
    accv += s_row[j] * xn[j * 64 + lane];
  }
  nx[w][lane] = accv;
  __syncthreads();
  if (tid < 64) {
    float s = 0.f;
#pragma unroll
    for (int w2 = 0; w2 < 8; w2++) s += nx[w2][tid];
    ws[WS_NEWX + i * 64 + tid] = s;
    int half = tid >> 5, col = tid & 31;
    float v = 0.f;
#pragma unroll
    for (int w2 = 0; w2 < 8; w2++) v += wred[half][w2][col];
    atomicAdd(&ws[WS_PART + tid], v);
  }
}

__global__ void __launch_bounds__(256) k5(const float* __restrict__ bn_n_w,
                                          const float* __restrict__ bn_n_b,
                                          const float* __restrict__ bn_e_w,
                                          const float* __restrict__ bn_e_b,
                                          const float* __restrict__ ws,
                                          float* __restrict__ out) {
  int blk = blockIdx.x, tid = threadIdx.x;
  if (blk < 8) {
    __shared__ float s1[4][64], s2[4][64], scl[64], shf[64];
    int c = tid & 63, g = tid >> 6;
    float a = 0.f, b = 0.f;
#pragma unroll 4
    for (int u = 0; u < 128; u++) {
      float v = ws[WS_NEWX + (g * 128 + u) * 64 + c];
      a += v;
      b += v * v;
    }
    s1[g][c] = a;
    s2[g][c] = b;
    __syncthreads();
    if (tid < 64) {
      float sum = s1[0][tid] + s1[1][tid] + s1[2][tid] + s1[3][tid];
      float ssq = s2[0][tid] + s2[1][tid] + s2[2][tid] + s2[3][tid];
      float mean = sum * (1.f / 512.f);
      float var = ssq * (1.f / 512.f) - mean * mean;
      float s = bn_n_w[tid] * rsqrtf(fmaxf(var, 0.f) + EPS);
      scl[tid] = s;
      shf[tid] = bn_n_b[tid] - mean * s;
    }
    __syncthreads();
#pragma unroll 4
    for (int u = 0; u < 16; u++) {
      int idx = blk * 4096 + u * 256 + tid;
      int c2 = idx & 63;
      out[idx] = ws[WS_NEWX + idx] * scl[c2] + shf[c2];
    }
  } else {
    __shared__ __attribute__((aligned(16))) float escsh[64];
    if (tid < 32) {
      float sum = ws[WS_PART + tid];
      float ssq = ws[WS_PART + 32 + tid];
      float mean = sum * (1.f / 262144.f);
      float var = ssq * (1.f / 262144.f) - mean * mean;
      float s = bn_e_w[tid] * rsqrtf(fmaxf(var, 0.f) + EPS);
      escsh[tid] = s;
      escsh[32 + tid] = bn_e_b[tid] - mean * s;
    }
    __syncthreads();
    const unsigned* ne32 = (const unsigned*)((const unsigned short*)ws + WSH_NE);
    int b4 = ((blk - 8) * 256 + tid) * 4;
    u32x4 raw = *(const u32x4*)(ne32 + b4);
    int e32 = (b4 >> 4) * 32;
    int cb = b4 & 15;
    f32x4 esc0 = *(const f32x4*)&escsh[cb];
    f32x4 esc1 = *(const f32x4*)&escsh[16 + cb];
    f32x4 esh0 = *(const f32x4*)&escsh[32 + cb];
    f32x4 esh1 = *(const f32x4*)&escsh[48 + cb];
    f32x4 lo, hi;
#pragma unroll
    for (int u = 0; u < 4; u++) {
      lo[u] = bf2f((unsigned short)(raw[u] & 0xffffu)) * esc0[u] + esh0[u];
      hi[u] = bf2f((unsigned short)(raw[u] >> 16)) * esc1[u] + esh1[u];
    }
    float* oe = out + 32768;
    *(f32x4*)(oe + e32 + cb) = lo;
    *(f32x4*)(oe + e32 + 16 + cb) = hi;
  }
}

extern "C" void kernel_launch(void* const* d_in, const int* in_sizes, int n_in,
                              void* d_out, int out_size, void* d_ws, size_t ws_size,
                              hipStream_t stream) {
  const float* x = (const float*)d_in[0];
  const float* ea = (const float*)d_in[1];
  const int* mask = (const int*)d_in[2];
  const float* Wnu = (const float*)d_in[3];
  const float* bnu = (const float*)d_in[4];
  const float* Wh2 = (const float*)d_in[5];
  const float* bh2 = (const float*)d_in[6];
  const float* Weo = (const float*)d_in[7];
  const float* beo = (const float*)d_in[8];
  const float* ev = (const float*)d_in[9];
  const float* bnw = (const float*)d_in[10];
  const float* bnb = (const float*)d_in[11];
  const float* bew = (const float*)d_in[12];
  const float* beb = (const float*)d_in[13];
  float* ws = (float*)d_ws;
  float* out = (float*)d_out;

  static int coop_state = -1;  // -1 unknown, 1 works, 0 fallback
  static int gblocks = 0;
  if (gblocks == 0) {
    int per = 0;
    if (hipOccupancyMaxActiveBlocksPerMultiprocessor(&per, kall, 512, 0) != hipSuccess ||
        per < 1)
      per = 1;
    int cus = 256;
    hipDeviceGetAttribute(&cus, hipDeviceAttributeMultiprocessorCount, 0);
    long g = (long)per * (long)cus;
    gblocks = (int)(g > 512 ? 512 : g);
    if (gblocks < 8) gblocks = 8;  // phase-3 node BN needs >= 8 blocks
  }

  if (coop_state != 0) {
    void* args[] = {(void*)&x,   (void*)&ea,  (void*)&mask, (void*)&Wnu,
                    (void*)&bnu, (void*)&Wh2, (void*)&bh2,  (void*)&Weo,
                    (void*)&beo, (void*)&ev,  (void*)&bnw,  (void*)&bnb,
                    (void*)&bew, (void*)&beb, (void*)&ws,   (void*)&out};
    hipError_t rc = hipLaunchCooperativeKernel(kall, dim3(gblocks), dim3(512), args,
                                               0, stream);
    if (rc == hipSuccess) {
      coop_state = 1;
      return;
    }
    coop_state = 0;  // fall through to 3-kernel path
  }

  k1<<<168, 256, 0, stream>>>(x, Wnu, bnu, Wh2, bh2, Weo, ev, ws);
  k2<<<512, 512, 0, stream>>>(ea, mask, beo, ev, ws);
  k5<<<4104, 256, 0, stream>>>(bnw, bnb, bew, beb, ws, out);
}

// Round 7
// 152.358 us; speedup vs baseline: 1.4978x; 1.4978x over previous
//
#include <hip/hip_runtime.h>

#define SLOPE 0.1f
#define EPS 1e-5f

typedef __bf16 bf16x8 __attribute__((ext_vector_type(8)));
typedef unsigned short u16x8 __attribute__((ext_vector_type(8)));
typedef float f32x4 __attribute__((ext_vector_type(4)));
typedef unsigned u32x4 __attribute__((ext_vector_type(4)));

// ---- workspace layout ----
// float offsets on (float*)ws:
#define WS_ESC 0        // 32 : (unused; kept for layout stability)
#define WS_ESH 32       // 32
#define WS_A 64         // 512 : dot(xn_i, ev[0:64])
#define WS_B 576        // 512 : dot(xn_j, ev[96:160])
#define WS_XN 1088      // 512*64 post-lrelu node feats
#define WS_NEWX 33856   // 512*64 pre-BN new_x
#define WS_P1B 66624    // 512*80 : b_h2[k] + x_i . W_h2[k][0:64]
#define WS_SC 107584    // (dead)
#define WS_PART 369728  // 64 floats: [0:32]=col sums, [32:64]=col sumsq (atomic)
// u16 offsets on (unsigned short*)ws (float end 402496 -> u16 804992).
// Weight tables FRAG-MAJOR: element (t, lane l, jj) at [t*512 + l*8 + jj],
// i.e. MFMA B-frag value: n = t*16 + (l&15), k = (l>>4)*8 + jj.
#define WSH_WB 804992   // 2*2560 : GEMM1 B chunks 0,1 (W_h2 cols 64:96, 96:128)
#define WSH_WB2 810112  // 2560   : GEMM1 B chunk 2    (W_h2 cols 128:160)
#define WSH_WO 812672   // 3072   : GEMM2 B (W_eo, k padded to 96)
#define WSH_XB 815744   // 512*64 bf16 copy of x (row-major)
#define WSH_NE 848512   // 262144 edges * 16 u32 (col c | col c+16), bf16 packed

__device__ __forceinline__ float lrelu(float v) { return v > 0.f ? v : SLOPE * v; }
__device__ __forceinline__ unsigned short f2bf(float f) {
  unsigned x = __float_as_uint(f);
  return (unsigned short)((x + 0x7fffu + ((x >> 16) & 1u)) >> 16);
}
__device__ __forceinline__ float bf2f(unsigned short u) {
  return __uint_as_float(((unsigned)u) << 16);
}

// ---------------- K1 ----------------
// blocks 0..127 : xn + a/b scalars + bf16 copies (x, frag-major weights) + zero stats
// blocks 128..167 : P1 via MFMA  (M=512 x N=80, K=64)
__global__ void __launch_bounds__(256) k1(const float* __restrict__ x,
                                          const float* __restrict__ W_nu,
                                          const float* __restrict__ b_nu,
                                          const float* __restrict__ W_h2,
                                          const float* __restrict__ b_h2,
                                          const float* __restrict__ W_eo,
                                          const float* __restrict__ ev,
                                          float* ws) {
  int blk = blockIdx.x;
  int tid = threadIdx.x;
  unsigned short* wsh = (unsigned short*)ws;
  if (blk < 128) {
    __shared__ float wlds[64 * 65];
#pragma unroll
    for (int it = 0; it < 16; it++) {
      int idx = it * 256 + tid;
      wlds[(idx >> 6) * 65 + (idx & 63)] = W_nu[idx];
    }
    int gid = blk * 256 + tid;  // 0..32767
    wsh[WSH_XB + gid] = f2bf(x[gid]);
    if (gid < 64) ws[WS_PART + gid] = 0.f;  // zero edge-BN stat accumulators
    if (gid < 5120) {
      int c = gid / 2560, r = gid - c * 2560;
      int t = r >> 9, l = (r >> 3) & 63, jj = r & 7;
      int n = t * 16 + (l & 15);
      int k = (l >> 4) * 8 + jj + c * 32;
      wsh[WSH_WB + gid] = f2bf(W_h2[n * 160 + 64 + k]);
    } else if (gid < 7680) {
      int idx = gid - 5120;
      int t = idx >> 9, l = (idx >> 3) & 63, jj = idx & 7;
      int n = t * 16 + (l & 15);
      int k = (l >> 4) * 8 + jj;
      wsh[WSH_WB2 + idx] = f2bf(W_h2[n * 160 + 128 + k]);
    } else if (gid < 10752) {
      int idx = gid - 7680;
      int t2 = idx / 1536, r2 = idx - t2 * 1536;
      int s = r2 >> 9, l = (r2 >> 3) & 63, jj = r2 & 7;
      int n = t2 * 16 + (l & 15);
      int k = s * 32 + (l >> 4) * 8 + jj;
      wsh[WSH_WO + idx] = (k < 80) ? f2bf(W_eo[n * 80 + k]) : (unsigned short)0;
    }
    __syncthreads();
    int i = blk * 4 + (tid >> 6);
    int c = tid & 63;
    float acc = b_nu[c];
    const float* xr = x + i * 64;
#pragma unroll 8
    for (int k = 0; k < 64; k++) acc += xr[k] * wlds[c * 65 + k];
    float xnv = lrelu(acc);
    ws[WS_XN + i * 64 + c] = xnv;
    float va = xnv * ev[c];
    float vb = xnv * ev[96 + c];
#pragma unroll
    for (int off = 32; off >= 1; off >>= 1) {
      va += __shfl_xor(va, off, 64);
      vb += __shfl_xor(vb, off, 64);
    }
    if (c == 0) { ws[WS_A + i] = va; ws[WS_B + i] = vb; }
  } else {
    // MFMA P1-GEMM: block covers 64 rows (bm) x 16 cols (bn) of N=80
    int b2 = blk - 128;             // 0..39
    int bm = b2 & 7, bn = b2 >> 3;  // M-tile of 64, N-tile of 16
    int wave = tid >> 6, lane = tid & 63;
    int c16 = lane & 15, q = lane >> 4;
    int n = bn * 16 + c16;  // 0..79
    const float* wrow = W_h2 + n * 160;
    int mrow = bm * 64 + wave * 16 + c16;
    bf16x8 bfr[2], afr[2];
#pragma unroll
    for (int ks = 0; ks < 2; ks++) {
      const float* bs = wrow + ks * 32 + q * 8;
      const float* as = x + mrow * 64 + ks * 32 + q * 8;
      u16x8 ub, ua;
#pragma unroll
      for (int jj = 0; jj < 8; jj++) { ub[jj] = f2bf(bs[jj]); ua[jj] = f2bf(as[jj]); }
      bfr[ks] = __builtin_bit_cast(bf16x8, ub);
      afr[ks] = __builtin_bit_cast(bf16x8, ua);
    }
    float bias = b_h2[n];
    f32x4 acc = {bias, bias, bias, bias};
    acc = __builtin_amdgcn_mfma_f32_16x16x32_bf16(afr[0], bfr[0], acc, 0, 0, 0);
    acc = __builtin_amdgcn_mfma_f32_16x16x32_bf16(afr[1], bfr[1], acc, 0, 0, 0);
#pragma unroll
    for (int r = 0; r < 4; r++) {
      int mm = bm * 64 + wave * 16 + q * 4 + r;
      ws[WS_P1B + mm * 80 + n] = acc[r];
    }
  }
}

// ---------------- K2: one block = one full row i (512 edges, 8 waves) ----------------
// Per wave: 4 sequential 16-edge tiles (GEMM1 K=96 MFMA -> lrelu -> GEMM2).
// Latency hiding: ALL 4 tiles' global inputs (ea, mask) are loaded up-front so
// tiles 1-3's HBM/L2 latency hides under tile 0's compute (k2 measured
// latency-bound: VALUBusy ~10%, MfmaUtil ~2% in r5 PMC). s_setprio(1) wraps the
// MFMA clusters (8 barrier-free staggered waves -> attn-like regime).
// Then IN-BLOCK: softmax over the row + att@xn -> NEWX; edge-BN stats via 64
// device atomicAdds.
__global__ void __launch_bounds__(512, 4) k2(const float* __restrict__ ea,
                                             const int* __restrict__ mask,
                                             const float* __restrict__ b_eo,
                                             const float* __restrict__ ev,
                                             float* ws) {
  __shared__ unsigned short wlds[10752];   // [ch0|ch1|ch2|wo] frag-major
  __shared__ unsigned short ht[128 * 104]; // 8 waves x 16-row stripes
  __shared__ float p1s[80];
  __shared__ float s_row[512];             // scores, then att weights
  __shared__ float red[8];
  __shared__ float nx[8][64];
  __shared__ float wred[2][8][32];
  int tid = threadIdx.x;
  int w = tid >> 6, lane = tid & 63;
  int c16 = lane & 15, q = lane >> 4;
  int i = blockIdx.x;  // row
  const unsigned short* wsh = (const unsigned short*)ws;
  unsigned* ne32 = (unsigned*)((unsigned short*)ws + WSH_NE);

  // stage weights: 1344 x 16B over 512 threads
#pragma unroll
  for (int it = 0; it < 3; it++) {
    int idx = it * 512 + tid;
    if (idx < 1344) *(u16x8*)&wlds[idx * 8] = *(const u16x8*)(wsh + WSH_WB + idx * 8);
  }
  if (tid < 80) p1s[tid] = ws[WS_P1B + i * 80 + tid];
  float beo0 = b_eo[c16], beo1 = b_eo[16 + c16];
  float eve0 = ev[64 + c16], eve1 = ev[80 + c16];
  float a_i = ws[WS_A + i];

  // ---- hoisted global inputs for all 4 tiles (latency hiding) ----
  f32x4 ea0[4], ea1[4];
  int4 mk4[4];
#pragma unroll
  for (int h = 0; h < 4; h++) {
    int jb = w * 64 + h * 16;
    const float* src = ea + (i * 512 + jb + c16) * 32 + q * 8;
    ea0[h] = *(const f32x4*)src;
    ea1[h] = *(const f32x4*)(src + 4);
    mk4[h] = *(const int4*)(mask + i * 512 + jb + q * 4);
  }
  __syncthreads();

  float scs0 = 0.f, scss0 = 0.f, scs1 = 0.f, scss1 = 0.f;

#pragma unroll
  for (int h = 0; h < 4; h++) {
    int jb = w * 64 + h * 16;  // this wave's 16-edge tile

    // A-frags: chunk0 = ea (pre-loaded), chunk1/2 = bf16 x_j (16B LDS-free loads)
    bf16x8 af0;
    {
      u16x8 u;
#pragma unroll
      for (int jj = 0; jj < 4; jj++) {
        u[jj] = f2bf(ea0[h][jj]);
        u[4 + jj] = f2bf(ea1[h][jj]);
      }
      af0 = __builtin_bit_cast(bf16x8, u);
    }
    bf16x8 af1 = __builtin_bit_cast(
        bf16x8, *(const u16x8*)(wsh + WSH_XB + (jb + c16) * 64 + q * 8));
    bf16x8 af2 = __builtin_bit_cast(
        bf16x8, *(const u16x8*)(wsh + WSH_XB + (jb + c16) * 64 + 32 + q * 8));
    int mkv[4];
    mkv[0] = mk4[h].x; mkv[1] = mk4[h].y; mkv[2] = mk4[h].z; mkv[3] = mk4[h].w;

    f32x4 acc[5];
#pragma unroll
    for (int t = 0; t < 5; t++) {
      float p1v = p1s[t * 16 + c16];
      acc[t] = {p1v, p1v, p1v, p1v};
    }
    __builtin_amdgcn_s_setprio(1);
#pragma unroll
    for (int t = 0; t < 5; t++) {
      bf16x8 wb = __builtin_bit_cast(bf16x8, *(const u16x8*)&wlds[t * 512 + lane * 8]);
      acc[t] = __builtin_amdgcn_mfma_f32_16x16x32_bf16(af0, wb, acc[t], 0, 0, 0);
    }
#pragma unroll
    for (int t = 0; t < 5; t++) {
      bf16x8 wb =
          __builtin_bit_cast(bf16x8, *(const u16x8*)&wlds[2560 + t * 512 + lane * 8]);
      acc[t] = __builtin_amdgcn_mfma_f32_16x16x32_bf16(af1, wb, acc[t], 0, 0, 0);
    }
#pragma unroll
    for (int t = 0; t < 5; t++) {
      bf16x8 wb =
          __builtin_bit_cast(bf16x8, *(const u16x8*)&wlds[5120 + t * 512 + lane * 8]);
      acc[t] = __builtin_amdgcn_mfma_f32_16x16x32_bf16(af2, wb, acc[t], 0, 0, 0);
    }
    __builtin_amdgcn_s_setprio(0);
    // lrelu -> ht (wave-private 16-row stripe; no barrier needed)
#pragma unroll
    for (int t = 0; t < 5; t++)
#pragma unroll
      for (int r = 0; r < 4; r++)
        ht[(w * 16 + q * 4 + r) * 104 + t * 16 + c16] = f2bf(lrelu(acc[t][r]));

    // GEMM2: ne = h @ W_eo^T
    f32x4 acc2[2] = {{0.f, 0.f, 0.f, 0.f}, {0.f, 0.f, 0.f, 0.f}};
    int hrow = w * 16 + c16;
    __builtin_amdgcn_s_setprio(1);
#pragma unroll
    for (int s = 0; s < 3; s++) {
      int kk = s * 32 + q * 8;
      u16x8 hb = {0, 0, 0, 0, 0, 0, 0, 0};
      if (kk < 80) hb = *(const u16x8*)&ht[hrow * 104 + kk];
      bf16x8 ha = __builtin_bit_cast(bf16x8, hb);
      bf16x8 wo0 =
          __builtin_bit_cast(bf16x8, *(const u16x8*)&wlds[7680 + s * 512 + lane * 8]);
      bf16x8 wo1 = __builtin_bit_cast(
          bf16x8, *(const u16x8*)&wlds[7680 + 1536 + s * 512 + lane * 8]);
      acc2[0] = __builtin_amdgcn_mfma_f32_16x16x32_bf16(ha, wo0, acc2[0], 0, 0, 0);
      acc2[1] = __builtin_amdgcn_mfma_f32_16x16x32_bf16(ha, wo1, acc2[1], 0, 0, 0);
    }
    __builtin_amdgcn_s_setprio(0);

    // epilogue: bias, lrelu, mask; packed bf16 store; col stats; scores
    float se[4];
#pragma unroll
    for (int r = 0; r < 4; r++) {
      int m = i * 512 + jb + q * 4 + r;
      float mf = mkv[r] ? 1.f : 0.f;
      float v0 = lrelu(acc2[0][r] + beo0) * mf;
      float v1 = lrelu(acc2[1][r] + beo1) * mf;
      scs0 += v0; scss0 += v0 * v0;
      scs1 += v1; scss1 += v1 * v1;
      ne32[m * 16 + c16] = (unsigned)f2bf(v0) | ((unsigned)f2bf(v1) << 16);
      float s = v0 * eve0 + v1 * eve1;
#pragma unroll
      for (int off = 8; off >= 1; off >>= 1) s += __shfl_xor(s, off, 64);
      se[r] = s;
    }
    if (c16 < 4) {
      int j = jb + q * 4 + c16;
      float s = (c16 == 0) ? se[0] : (c16 == 1) ? se[1] : (c16 == 2) ? se[2] : se[3];
      s_row[j] = lrelu(a_i + ws[WS_B + j] + s);
    }
  }

  // wave stats -> wred (per-wave totals over its 64 edges)
  scs0 += __shfl_xor(scs0, 16, 64); scs0 += __shfl_xor(scs0, 32, 64);
  scss0 += __shfl_xor(scss0, 16, 64); scss0 += __shfl_xor(scss0, 32, 64);
  scs1 += __shfl_xor(scs1, 16, 64); scs1 += __shfl_xor(scs1, 32, 64);
  scss1 += __shfl_xor(scss1, 16, 64); scss1 += __shfl_xor(scss1, 32, 64);
  if (q == 0) {
    wred[0][w][c16] = scs0; wred[0][w][16 + c16] = scs1;
    wred[1][w][c16] = scss0; wred[1][w][16 + c16] = scss1;
  }
  __syncthreads();  // s_row + wred complete

  // ---- softmax over the row (no max-subtraction: scores bounded; shift-inv.)
  float p = __expf(s_row[tid]);
  float sm = p;
#pragma unroll
  for (int off = 32; off >= 1; off >>= 1) sm += __shfl_xor(sm, off, 64);
  if (lane == 0) red[w] = sm;
  __syncthreads();
  float tot = red[0] + red[1] + red[2] + red[3] + red[4] + red[5] + red[6] + red[7];
  float attv = p * (1.f / tot) * (mask[i * 512 + tid] ? 1.f : 0.f);
  s_row[tid] = attv;
  __syncthreads();

  // ---- att @ xn : wave w covers j in [w*64, (w+1)*64)
  const float* xn = ws + WS_XN;
  float accv = 0.f;
#pragma unroll 4
  for (int u = 0; u < 64; u++) {
    int j = w * 64 + u;
    accv += s_row[j] * xn[j * 64 + lane];
  }
  nx[w][lane] = accv;
  __syncthreads();
  if (tid < 64) {
    float s = 0.f;
#pragma unroll
    for (int w2 = 0; w2 < 8; w2++) s += nx[w2][tid];
    ws[WS_NEWX + i * 64 + tid] = s;
    // edge-BN stats: one atomic per (stat,col) per block into the 64 totals
    int half = tid >> 5, col = tid & 31;
    float v = 0.f;
#pragma unroll
    for (int w2 = 0; w2 < 8; w2++) v += wred[half][w2][col];
    atomicAdd(&ws[WS_PART + tid], v);
  }
}

// ---------------- K5: node BN (blocks 0..7) + edge BN apply (4096 blocks) ----------------
// Edge blocks derive esc/esh locally from the 64-float atomic totals (L2-hot).
__global__ void __launch_bounds__(256) k5(const float* __restrict__ bn_n_w,
                                          const float* __restrict__ bn_n_b,
                                          const float* __restrict__ bn_e_w,
                                          const float* __restrict__ bn_e_b,
                                          const float* __restrict__ ws,
                                          float* __restrict__ out) {
  int blk = blockIdx.x, tid = threadIdx.x;
  if (blk < 8) {
    __shared__ float s1[4][64], s2[4][64], scl[64], sh[64];
    int c = tid & 63, g = tid >> 6;
    float a = 0.f, b = 0.f;
#pragma unroll 4
    for (int u = 0; u < 128; u++) {
      float v = ws[WS_NEWX + (g * 128 + u) * 64 + c];
      a += v;
      b += v * v;
    }
    s1[g][c] = a;
    s2[g][c] = b;
    __syncthreads();
    if (tid < 64) {
      float sum = s1[0][tid] + s1[1][tid] + s1[2][tid] + s1[3][tid];
      float ssq = s2[0][tid] + s2[1][tid] + s2[2][tid] + s2[3][tid];
      float mean = sum * (1.f / 512.f);
      float var = ssq * (1.f / 512.f) - mean * mean;
      float s = bn_n_w[tid] * rsqrtf(fmaxf(var, 0.f) + EPS);
      scl[tid] = s;
      sh[tid] = bn_n_b[tid] - mean * s;
    }
    __syncthreads();
#pragma unroll 4
    for (int u = 0; u < 16; u++) {
      int idx = blk * 4096 + u * 256 + tid;
      int c2 = idx & 63;
      out[idx] = ws[WS_NEWX + idx] * scl[c2] + sh[c2];
    }
  } else {
    __shared__ __attribute__((aligned(16))) float escsh[64];
    if (tid < 32) {
      float sum = ws[WS_PART + tid];
      float ssq = ws[WS_PART + 32 + tid];
      float mean = sum * (1.f / 262144.f);
      float var = ssq * (1.f / 262144.f) - mean * mean;
      float s = bn_e_w[tid] * rsqrtf(fmaxf(var, 0.f) + EPS);
      escsh[tid] = s;
      escsh[32 + tid] = bn_e_b[tid] - mean * s;
    }
    __syncthreads();
    const unsigned* ne32 = (const unsigned*)((const unsigned short*)ws + WSH_NE);
    int b4 = ((blk - 8) * 256 + tid) * 4;  // u32 index
    u32x4 raw = *(const u32x4*)(ne32 + b4);
    int e32 = (b4 >> 4) * 32;
    int cb = b4 & 15;  // 0,4,8,12
    f32x4 esc0 = *(const f32x4*)&escsh[cb];
    f32x4 esc1 = *(const f32x4*)&escsh[16 + cb];
    f32x4 esh0 = *(const f32x4*)&escsh[32 + cb];
    f32x4 esh1 = *(const f32x4*)&escsh[48 + cb];
    f32x4 lo, hi;
#pragma unroll
    for (int u = 0; u < 4; u++) {
      lo[u] = bf2f((unsigned short)(raw[u] & 0xffffu)) * esc0[u] + esh0[u];
      hi[u] = bf2f((unsigned short)(raw[u] >> 16)) * esc1[u] + esh1[u];
    }
    float* oe = out + 32768;
    *(f32x4*)(oe + e32 + cb) = lo;
    *(f32x4*)(oe + e32 + 16 + cb) = hi;
  }
}

extern "C" void kernel_launch(void* const* d_in, const int* in_sizes, int n_in,
                              void* d_out, int out_size, void* d_ws, size_t ws_size,
                              hipStream_t stream) {
  const float* x = (const float*)d_in[0];
  const float* ea = (const float*)d_in[1];
  const int* mask = (const int*)d_in[2];
  const float* Wnu = (const float*)d_in[3];
  const float* bnu = (const float*)d_in[4];
  const float* Wh2 = (const float*)d_in[5];
  const float* bh2 = (const float*)d_in[6];
  const float* Weo = (const float*)d_in[7];
  const float* beo = (const float*)d_in[8];
  const float* ev = (const float*)d_in[9];
  const float* bnw = (const float*)d_in[10];
  const float* bnb = (const float*)d_in[11];
  const float* bew = (const float*)d_in[12];
  const float* beb = (const float*)d_in[13];
  float* ws = (float*)d_ws;
  float* out = (float*)d_out;

  k1<<<168, 256, 0, stream>>>(x, Wnu, bnu, Wh2, bh2, Weo, ev, ws);
  k2<<<512, 512, 0, stream>>>(ea, mask, beo, ev, ws);
  k5<<<4104, 256, 0, stream>>>(bnw, bnb, bew, beb, ws, out);
}